// Round 10
// baseline (158.969 us; speedup 1.0000x reference)
//
#include <hip/hip_runtime.h>

// Event-warp + bilinear splat, v10.
//   K1 ssort : source-tile counting scatter (R7 form: 512 thr, shared hist,
//              padded global cursors). No flow read.
//   K2 splat_gather : FUSED build+splat. One block per ownership tile reads
//              the <=9 source-tile record ranges in its 3x3 ring, recomputes
//              the warp (flow from global; wave-local source tile => L1
//              locality), keeps only owned corners, accumulates (w, w*nts)
//              Q20-packed via ONE ds_add_u64 per corner, applies ssort spill,
//              writes out with pure float4 stores (no out-memset needed).
// Inputs (setup_inputs order):
//   d_in[0] flow  : float32 [B,2,H,W]   (ch0 = x-flow, ch1 = y-flow)
//   d_in[1] ts    : float32 [B,N,1]
//   d_in[2] ev_y  : int32   [B,N]
//   d_in[3] ev_x  : int32   [B,N]
//   d_in[4] pol   : int32   [B,N]  (1 = positive, 0 = negative)
// Output: float32 [B,4,H,W] = (iwe_pos, iwe_neg, iwe_pos_ts, iwe_neg_ts)

#define IMG_H 480
#define IMG_W 640

#define OT_H 16
#define OT_W 32
#define OTY (IMG_H / OT_H)        // 30
#define OTX (IMG_W / OT_W)        // 20
#define OT_PER_B (OTY * OTX)      // 600
#define NB 4
#define NT (NB * OT_PER_B)        // 2400

#define ACC_PLANE (OT_H * OT_W)   // 512 cells

// ws layout (byte offsets)
#define SCURS_STRIDE 16                 // u32 stride -> 64 B padded lines
#define WS_SCURS 0                      // NT * 64 B = 153600
#define WS_SPILLCNT 163200              // 4 B
#define WS_SPILL 163840                 // SPILL_CAP * 16 B = 512 KB
#define SPILL_CAP 32768
#define WS_RECS 688128                  // srecs: NT * cap * 8 B

#define SSORT_THREADS 512
#define K1_IPT 2
#define K1_CHUNK (SSORT_THREADS * K1_IPT)   // 1024 events per block

#define Q20 1048576.0f
#define INV_Q20 9.5367431640625e-07f

// ---------------------------------------------------------------------------
__device__ __forceinline__ void
warp_from(const float* __restrict__ flow, int b, int y, int x, float t,
          float& wy, float& wx, float& nts) {
    const float* fb = flow + (size_t)b * 2 * IMG_H * IMG_W;
    const int pix = y * IMG_W + x;
    const float fx = fb[pix];
    const float fy = fb[IMG_H * IMG_W + pix];
    const float dt = 1.0f - t;
    wy = (float)y + dt * fy;
    wx = (float)x + dt * fx;
    nts = 1.0f - fabsf(1.0f - t);
}

// ---------------------------------------------------------------------------
// K1: counting-scatter by SOURCE tile (key from ev_y/ev_x directly).
__global__ void __launch_bounds__(SSORT_THREADS)
ssort_kernel(const float* __restrict__ flow, const float* __restrict__ ts,
             const int* __restrict__ ev_y, const int* __restrict__ ev_x,
             const int* __restrict__ pol,
             unsigned* __restrict__ scurs, unsigned* __restrict__ spillcnt,
             float4* __restrict__ spill, uint2* __restrict__ srecs,
             int N, int cap) {
    __shared__ unsigned lh[OT_PER_B];
    __shared__ unsigned lbase[OT_PER_B];
    const int tid = threadIdx.x;
    const int b = blockIdx.y;
    const int base = blockIdx.x * K1_CHUNK;

    for (int j = tid; j < OT_PER_B; j += SSORT_THREADS) lh[j] = 0;
    __syncthreads();

    unsigned mK[K1_IPT], ltK[K1_IPT], rkK[K1_IPT];
    float tsK[K1_IPT];

    #pragma unroll
    for (int k = 0; k < K1_IPT; ++k) {
        const int idx = base + k * SSORT_THREADS + tid;
        unsigned lt = 0xFFFFu, rk = 0, m = 0; float t = 0.f;
        if (idx < N) {
            const int i = b * N + idx;
            const int y = ev_y[i];
            const int x = ev_x[i];
            t = ts[i];
            const int p = pol[i];
            lt = (unsigned)((y >> 4) * OTX + (x >> 5));
            rk = atomicAdd(&lh[lt], 1u);
            m = (unsigned)y | ((unsigned)x << 9) | ((unsigned)(p & 1) << 19);
        }
        mK[k] = m; ltK[k] = lt; rkK[k] = rk; tsK[k] = t;
    }
    __syncthreads();

    for (int j = tid; j < OT_PER_B; j += SSORT_THREADS) {
        const unsigned n = lh[j];
        lbase[j] = n ? atomicAdd(&scurs[(size_t)(b * OT_PER_B + j) * SCURS_STRIDE], n)
                     : 0u;
    }
    __syncthreads();

    #pragma unroll
    for (int k = 0; k < K1_IPT; ++k) {
        const unsigned lt = ltK[k];
        if (lt == 0xFFFFu) continue;
        const unsigned slot = lbase[lt] + rkK[k];
        if (slot < (unsigned)cap) {
            uint2 r; r.x = mK[k]; r.y = __float_as_uint(tsK[k]);
            srecs[(size_t)(b * OT_PER_B + lt) * cap + slot] = r;
        } else {
            // rare: process fully now, defer via unrestricted spill
            const int y = (int)(mK[k] & 511u);
            const int x = (int)((mK[k] >> 9) & 1023u);
            const int p = (int)((mK[k] >> 19) & 1u);
            float wy, wx, nts;
            warp_from(flow, b, y, x, tsK[k], wy, wx, nts);
            const unsigned g = atomicAdd(spillcnt, 1u);
            if (g < SPILL_CAP) {
                float4 s; s.x = wy; s.y = wx; s.z = nts;
                s.w = __uint_as_float((unsigned)((b << 1) | p));  // bit31=0
                spill[g] = s;
            }
        }
    }
}

// ---------------------------------------------------------------------------
// K2: fused build+splat, dest-side gather over the 3x3 source ring.
__global__ void __launch_bounds__(256)
splat_gather_kernel(const float* __restrict__ flow,
                    const uint2* __restrict__ srecs,
                    const unsigned* __restrict__ scurs,
                    const float4* __restrict__ spill,
                    const unsigned* __restrict__ spillcnt,
                    float* __restrict__ out, int cap) {
    __shared__ unsigned long long acc64[2 * ACC_PLANE];  // [pol(pos,neg)][cell]
    const int tile = blockIdx.x;
    const int tid = threadIdx.x;
    #pragma unroll
    for (int j = tid; j < 2 * ACC_PLANE; j += 256) acc64[j] = 0ull;
    __syncthreads();

    const int b  = tile / OT_PER_B;
    const int rb = tile % OT_PER_B;
    const int sy = rb / OTX;
    const int sx = rb % OTX;

    const float* fb = flow + (size_t)b * 2 * IMG_H * IMG_W;
    const int sty0 = max(sy - 1, 0), sty1 = min(sy + 1, OTY - 1);
    const int stx0 = max(sx - 1, 0), stx1 = min(sx + 1, OTX - 1);

    for (int sty = sty0; sty <= sty1; ++sty) {
        for (int stx = stx0; stx <= stx1; ++stx) {
            const int st = b * OT_PER_B + sty * OTX + stx;
            const unsigned cnt = min(scurs[(size_t)st * SCURS_STRIDE],
                                     (unsigned)cap);
            const uint2* base = srecs + (size_t)st * cap;
            for (unsigned i = tid; i < cnt; i += 256) {
                const uint2 sr = base[i];
                const int y = (int)(sr.x & 511u);
                const int x = (int)((sr.x >> 9) & 1023u);
                const int p = (int)((sr.x >> 19) & 1u);
                const float t = __uint_as_float(sr.y);
                const int pix = y * IMG_W + x;
                const float fx = fb[pix];
                const float fy = fb[IMG_H * IMG_W + pix];
                const float dt = 1.0f - t;
                const float wy = (float)y + dt * fy;
                const float wx = (float)x + dt * fx;
                const float nts = 1.0f - fabsf(1.0f - t);

                const float byf = floorf(wy), bxf = floorf(wx);
                const int iy0 = (int)byf, ix0 = (int)bxf;
                const float ay = wy - byf, ax = wx - bxf;
                const float wyv[2] = {1.0f - ay, ay};
                const float wxv[2] = {1.0f - ax, ax};
                unsigned long long* accp = acc64 + (p ? 0 : 1) * ACC_PLANE;
                #pragma unroll
                for (int dy = 0; dy < 2; ++dy) {
                    const int gy = iy0 + dy;
                    if ((gy >> 4) != sy) continue;     // ownership + OOB
                    #pragma unroll
                    for (int dx = 0; dx < 2; ++dx) {
                        const int gx = ix0 + dx;
                        if ((gx >> 5) != sx) continue;
                        const float w = wyv[dy] * wxv[dx];
                        const unsigned qw  = __float2uint_rn(w * Q20);
                        const unsigned qwt = __float2uint_rn(w * nts * Q20);
                        atomicAdd(&accp[(gy & 15) * OT_W + (gx & 31)],
                                  ((unsigned long long)qwt << 32)
                                  | (unsigned long long)qw);
                    }
                }
            }
        }
    }

    // spill application (normally zero records)
    const unsigned nsp = min(*spillcnt, (unsigned)SPILL_CAP);
    for (unsigned i = tid; i < nsp; i += 256) {
        const float4 s = spill[i];
        const unsigned meta = __float_as_uint(s.w);
        if ((int)((meta >> 1) & 3u) != b) continue;
        if (meta & 0x80000000u) {   // restricted variant (not produced in v10)
            if ((int)((meta >> 8) & 31u) != sy || (int)((meta >> 16) & 31u) != sx)
                continue;
        }
        const int p = (int)(meta & 1u);
        const float wy = s.x, wx = s.y, nts = s.z;
        const float byf = floorf(wy), bxf = floorf(wx);
        const int iy0 = (int)byf, ix0 = (int)bxf;
        const float ay = wy - byf, ax = wx - bxf;
        const float wyv[2] = {1.0f - ay, ay};
        const float wxv[2] = {1.0f - ax, ax};
        unsigned long long* accp = acc64 + (p ? 0 : 1) * ACC_PLANE;
        #pragma unroll
        for (int dy = 0; dy < 2; ++dy) {
            const int gy = iy0 + dy;
            if ((gy >> 4) != sy) continue;
            #pragma unroll
            for (int dx = 0; dx < 2; ++dx) {
                const int gx = ix0 + dx;
                if ((gx >> 5) != sx) continue;
                const float w = wyv[dy] * wxv[dx];
                const unsigned qw  = __float2uint_rn(w * Q20);
                const unsigned qwt = __float2uint_rn(w * nts * Q20);
                atomicAdd(&accp[(gy & 15) * OT_W + (gx & 31)],
                          ((unsigned long long)qwt << 32) | (unsigned long long)qw);
            }
        }
    }
    __syncthreads();

    const int y0 = sy * OT_H;
    const int x0 = sx * OT_W;
    float* outb = out + (size_t)b * 4 * IMG_H * IMG_W;
    {
        const int q = tid;                       // 0..255
        const int pl  = q / (ACC_PLANE / 4);     // 0 = pos, 1 = neg
        const int rem = q % (ACC_PLANE / 4);
        const int ry  = rem / (OT_W / 4);
        const int rx4 = rem % (OT_W / 4);
        float4 c4, t4;
        const unsigned long long* cell = acc64 + pl * ACC_PLANE + rem * 4;
        float* c = &c4.x; float* t = &t4.x;
        #pragma unroll
        for (int j = 0; j < 4; ++j) {
            const unsigned long long v = cell[j];
            c[j] = (float)(unsigned)(v & 0xFFFFFFFFull) * INV_Q20;
            t[j] = (float)(unsigned)(v >> 32) * INV_Q20;
        }
        const size_t off = (size_t)(y0 + ry) * IMG_W + x0 + rx4 * 4;
        *(float4*)(outb + (size_t)pl * IMG_H * IMG_W + off) = c4;
        *(float4*)(outb + (size_t)(pl + 2) * IMG_H * IMG_W + off) = t4;
    }
}

// ---------------------------------------------------------------------------
// Last-resort fallback: direct global atomics (needs zeroed out).
__global__ void __launch_bounds__(256)
event_splat_fallback(const float* __restrict__ flow, const float* __restrict__ ts,
                     const int* __restrict__ ev_y, const int* __restrict__ ev_x,
                     const int* __restrict__ pol, float* __restrict__ out,
                     int N, int total) {
    const int i = blockIdx.x * blockDim.x + threadIdx.x;
    if (i >= total) return;
    const int b = i / N;
    float wy, wx, nts;
    warp_from(flow, b, ev_y[i], ev_x[i], ts[i], wy, wx, nts);
    const int p = pol[i];
    const float byf = floorf(wy), bxf = floorf(wx);
    const int iy0 = (int)byf, ix0 = (int)bxf;
    const float ay = wy - byf, ax = wx - bxf;
    const float wyv[2] = {1.0f - ay, ay};
    const float wxv[2] = {1.0f - ax, ax};
    float* out_c = out + ((size_t)b * 4 + (p ? 0 : 1)) * IMG_H * IMG_W;
    float* out_t = out_c + 2 * IMG_H * IMG_W;
    #pragma unroll
    for (int dy = 0; dy < 2; ++dy) {
        const int gy = iy0 + dy;
        if (gy < 0 || gy >= IMG_H) continue;
        #pragma unroll
        for (int dx = 0; dx < 2; ++dx) {
            const int gx = ix0 + dx;
            if (gx < 0 || gx >= IMG_W) continue;
            const float w = wyv[dy] * wxv[dx];
            const int o = gy * IMG_W + gx;
            atomicAdd(out_c + o, w);
            atomicAdd(out_t + o, w * nts);
        }
    }
}

// ---------------------------------------------------------------------------
extern "C" void kernel_launch(void* const* d_in, const int* in_sizes, int n_in,
                              void* d_out, int out_size, void* d_ws, size_t ws_size,
                              hipStream_t stream) {
    const float* flow = (const float*)d_in[0];
    const float* ts   = (const float*)d_in[1];
    const int*   ev_y = (const int*)d_in[2];
    const int*   ev_x = (const int*)d_in[3];
    const int*   pol  = (const int*)d_in[4];
    float* out = (float*)d_out;

    const int total = in_sizes[2];                  // B*N
    const int B = out_size / (4 * IMG_H * IMG_W);
    const int N = total / B;
    char* ws = (char*)d_ws;

    // cap slots per tile: srec only now, 8 B/slot/tile.
    int cap = 0;
    if (ws_size > (size_t)WS_RECS)
        cap = (int)((ws_size - WS_RECS) / ((size_t)NT * 8));
    if (cap > 1024) cap = 1024;
    cap &= ~3;

    if (B == NB && cap >= 640) {
        unsigned* scurs    = (unsigned*)(ws + WS_SCURS);
        unsigned* spillcnt = (unsigned*)(ws + WS_SPILLCNT);
        float4*   spill    = (float4*)(ws + WS_SPILL);
        uint2*    srecs    = (uint2*)(ws + WS_RECS);

        hipMemsetAsync(ws, 0, WS_SPILL, stream);    // scurs + spillcnt

        dim3 g1((N + K1_CHUNK - 1) / K1_CHUNK, NB);
        ssort_kernel<<<g1, SSORT_THREADS, 0, stream>>>(flow, ts, ev_y, ev_x, pol,
                                                       scurs, spillcnt, spill,
                                                       srecs, N, cap);
        splat_gather_kernel<<<NT, 256, 0, stream>>>(flow, srecs, scurs,
                                                    spill, spillcnt, out, cap);
        return;
    }

    // last resort
    hipMemsetAsync(d_out, 0, (size_t)out_size * sizeof(float), stream);
    const int blocks = (total + 255) / 256;
    event_splat_fallback<<<blocks, 256, 0, stream>>>(flow, ts, ev_y, ev_x, pol,
                                                     out, N, total);
}

// Round 11
// 144.691 us; speedup vs baseline: 1.0987x; 1.0987x over previous
//
#include <hip/hip_runtime.h>

// Event-warp + bilinear splat, v11 — TWO passes.
//   K1 warp_scatter: one pass over events: warp (random flow gather,
//       L2/L3-resident), compute dest ownership tile(s) (dup ~1.096x for
//       straddlers), LDS hist+rank over 600 dest bins (v7-ssort machinery),
//       one padded global cursor atomic per nonzero (block,tile), write 8-B
//       dest-quantized records (v7 drec format). Overflow -> restricted spill.
//   K2 splat: one block per ownership tile; paired uint4 record loads;
//       (w, w*nts) Q20-packed into ONE ds_add_u64 per corner; fused spill
//       application; pure float4 writeout (no out-memset needed).
// Inputs (setup_inputs order):
//   d_in[0] flow  : float32 [B,2,H,W]   (ch0 = x-flow, ch1 = y-flow)
//   d_in[1] ts    : float32 [B,N,1]
//   d_in[2] ev_y  : int32   [B,N]
//   d_in[3] ev_x  : int32   [B,N]
//   d_in[4] pol   : int32   [B,N]  (1 = positive, 0 = negative)
// Output: float32 [B,4,H,W] = (iwe_pos, iwe_neg, iwe_pos_ts, iwe_neg_ts)

#define IMG_H 480
#define IMG_W 640

#define OT_H 16
#define OT_W 32
#define OTY (IMG_H / OT_H)        // 30
#define OTX (IMG_W / OT_W)        // 20
#define OT_PER_B (OTY * OTX)      // 600
#define NB 4
#define NT (NB * OT_PER_B)        // 2400

#define ACC_PLANE (OT_H * OT_W)   // 512 cells

// ws layout (byte offsets)
#define CURS_STRIDE 16                  // u32 stride -> 64 B padded lines
#define WS_CURS 0                       // NT * 64 B = 153600
#define WS_SPILLCNT 163200              // 4 B
#define WS_SPILL 163840                 // SPILL_CAP * 16 B = 512 KB
#define SPILL_CAP 32768
#define WS_RECS 688128                  // drecs: NT * cap * 8 B

#define K1_THREADS 256
#define K1_IPT 4
#define K1_CHUNK (K1_THREADS * K1_IPT)  // 1024 events per block

#define Q20 1048576.0f
#define INV_Q20 9.5367431640625e-07f

// ---------------------------------------------------------------------------
__device__ __forceinline__ void
warp_from(const float* __restrict__ flow, int b, int y, int x, float t,
          float& wy, float& wx, float& nts) {
    const float* fb = flow + (size_t)b * 2 * IMG_H * IMG_W;
    const int pix = y * IMG_W + x;
    const float fx = fb[pix];
    const float fy = fb[IMG_H * IMG_W + pix];
    const float dt = 1.0f - t;
    wy = (float)y + dt * fy;
    wx = (float)x + dt * fx;
    nts = 1.0f - fabsf(1.0f - t);
}

// ---------------------------------------------------------------------------
// K1: warp + direct dest-tile counting scatter.
__global__ void __launch_bounds__(K1_THREADS)
warp_scatter_kernel(const float* __restrict__ flow, const float* __restrict__ ts,
                    const int* __restrict__ ev_y, const int* __restrict__ ev_x,
                    const int* __restrict__ pol,
                    unsigned* __restrict__ dcurs, unsigned* __restrict__ spillcnt,
                    float4* __restrict__ spill, uint2* __restrict__ drecs,
                    int N, int cap) {
    __shared__ unsigned lh[OT_PER_B];     // per-dest-tile block-local counts
    __shared__ unsigned lbase[OT_PER_B];  // reserved global bases
    const int tid = threadIdx.x;
    const int b = blockIdx.y;
    const int base = blockIdx.x * K1_CHUNK;

    for (int j = tid; j < OT_PER_B; j += K1_THREADS) lh[j] = 0;
    __syncthreads();

    // Phase A: warp + LDS rank. Per event keep wy,wx, meta, and <=4 dups
    // packed as (lt << 16 | rank)  (lt < 600, rank < 1024).
    float wyK[K1_IPT], wxK[K1_IPT];
    unsigned metaK[K1_IPT];               // qt | pol<<15 (drec.y)
    unsigned ndK[K1_IPT];
    unsigned dupK[K1_IPT][4];

    #pragma unroll
    for (int k = 0; k < K1_IPT; ++k) {
        unsigned nd = 0;
        float wy = 0.f, wx = 0.f;
        unsigned meta = 0;
        const int idx = base + k * K1_THREADS + tid;
        if (idx < N) {
            const int i = b * N + idx;
            float nts;
            warp_from(flow, b, ev_y[i], ev_x[i], ts[i], wy, wx, nts);
            const int p = pol[i] & 1;
            int qt = __float2int_rn(nts * 32767.0f);
            qt = min(max(qt, 0), 32767);
            meta = (unsigned)qt | ((unsigned)p << 15);

            const int iy0 = (int)floorf(wy);
            const int ix0 = (int)floorf(wx);
            int rys[2]; int nry = 0;
            if (iy0 >= 0 && iy0 < IMG_H) rys[nry++] = iy0 >> 4;
            if (iy0 + 1 >= 0 && iy0 + 1 < IMG_H) {
                const int r = (iy0 + 1) >> 4;
                if (nry == 0 || r != rys[0]) rys[nry++] = r;
            }
            int rxs[2]; int nrx = 0;
            if (ix0 >= 0 && ix0 < IMG_W) rxs[nrx++] = ix0 >> 5;
            if (ix0 + 1 >= 0 && ix0 + 1 < IMG_W) {
                const int r = (ix0 + 1) >> 5;
                if (nrx == 0 || r != rxs[0]) rxs[nrx++] = r;
            }
            for (int a = 0; a < nry; ++a)
                for (int c = 0; c < nrx; ++c) {
                    const unsigned lt = (unsigned)(rys[a] * OTX + rxs[c]);
                    const unsigned rk = atomicAdd(&lh[lt], 1u);
                    dupK[k][nd++] = (lt << 16) | rk;
                }
        }
        wyK[k] = wy; wxK[k] = wx; metaK[k] = meta; ndK[k] = nd;
    }
    __syncthreads();

    // Phase B: reserve per-tile global ranges (1 padded atomic per nonzero)
    for (int j = tid; j < OT_PER_B; j += K1_THREADS) {
        const unsigned n = lh[j];
        lbase[j] = n ? atomicAdd(&dcurs[(size_t)(b * OT_PER_B + j) * CURS_STRIDE], n)
                     : 0u;
    }
    __syncthreads();

    // Phase C: write dest-quantized records
    #pragma unroll
    for (int k = 0; k < K1_IPT; ++k) {
        const unsigned nd = ndK[k];
        for (unsigned d = 0; d < nd; ++d) {
            const unsigned lt = dupK[k][d] >> 16;
            const unsigned rk = dupK[k][d] & 0xFFFFu;
            const int dty = (int)(lt / OTX);
            const int dtx = (int)(lt % OTX);
            const unsigned slot = lbase[lt] + rk;
            if (slot < (unsigned)cap) {
                int qy = __float2int_rn((wyK[k] - 16.0f * dty + 1.0f) * 2048.0f);
                int qx = __float2int_rn((wxK[k] - 32.0f * dtx + 1.0f) * 1024.0f);
                qy = min(max(qy, 0), 65535);
                qx = min(max(qx, 0), 65535);
                uint2 dr;
                dr.x = (unsigned)qy | ((unsigned)qx << 16);
                dr.y = metaK[k];
                drecs[(size_t)(b * OT_PER_B + lt) * cap + slot] = dr;
            } else {
                // restricted spill: applied only by tile (dty,dtx)
                const unsigned g = atomicAdd(spillcnt, 1u);
                if (g < SPILL_CAP) {
                    float4 s;
                    s.x = wyK[k]; s.y = wxK[k];
                    s.z = (float)(metaK[k] & 0x7FFFu) * (1.0f / 32767.0f);
                    s.w = __uint_as_float(0x80000000u
                            | (unsigned)((b << 1) | (metaK[k] >> 15))
                            | ((unsigned)dty << 8) | ((unsigned)dtx << 16));
                    spill[g] = s;
                }
            }
        }
    }
}

// ---------------------------------------------------------------------------
// K2: one block per ownership tile (v9-proven splat).
__device__ __forceinline__ void
splat_rec(unsigned rx_, unsigned ry_, unsigned long long* __restrict__ acc64) {
    const float ry  = (float)(rx_ & 0xFFFFu) * (1.0f / 2048.0f) - 1.0f;
    const float rx  = (float)(rx_ >> 16)     * (1.0f / 1024.0f) - 1.0f;
    const float nts = (float)(ry_ & 0x7FFFu) * (1.0f / 32767.0f);
    const int p = (int)((ry_ >> 15) & 1u);
    const float byf = floorf(ry), bxf = floorf(rx);
    const int iy0 = (int)byf, ix0 = (int)bxf;
    const float ay = ry - byf, ax = rx - bxf;
    const float wyv[2] = {1.0f - ay, ay};
    const float wxv[2] = {1.0f - ax, ax};
    unsigned long long* accp = acc64 + (p ? 0 : 1) * ACC_PLANE;
    #pragma unroll
    for (int dy = 0; dy < 2; ++dy) {
        const int gy = iy0 + dy;
        if ((unsigned)gy >= (unsigned)OT_H) continue;
        #pragma unroll
        for (int dx = 0; dx < 2; ++dx) {
            const int gx = ix0 + dx;
            if ((unsigned)gx >= (unsigned)OT_W) continue;
            const float w = wyv[dy] * wxv[dx];
            const unsigned qw  = __float2uint_rn(w * Q20);
            const unsigned qwt = __float2uint_rn(w * nts * Q20);
            atomicAdd(&accp[gy * OT_W + gx],
                      ((unsigned long long)qwt << 32) | (unsigned long long)qw);
        }
    }
}

__global__ void __launch_bounds__(256)
splat_kernel(const uint2* __restrict__ drecs, const unsigned* __restrict__ dcurs,
             const float4* __restrict__ spill, const unsigned* __restrict__ spillcnt,
             float* __restrict__ out, int cap) {
    __shared__ unsigned long long acc64[2 * ACC_PLANE];  // [pol(pos,neg)][cell]
    const int tile = blockIdx.x;
    const int tid = threadIdx.x;
    #pragma unroll
    for (int j = tid; j < 2 * ACC_PLANE; j += 256) acc64[j] = 0ull;
    __syncthreads();

    const int myb = tile / OT_PER_B;
    const int rb  = tile % OT_PER_B;
    const int sy  = rb / OTX;
    const int sx  = rb % OTX;

    const unsigned cnt = min(dcurs[(size_t)tile * CURS_STRIDE], (unsigned)cap);
    const uint2* recs = drecs + (size_t)tile * cap;
    const uint4* base4 = (const uint4*)recs;
    const unsigned npair = cnt >> 1;
    for (unsigned u = tid; u < npair; u += 256) {
        const uint4 q = base4[u];          // two records
        splat_rec(q.x, q.y, acc64);
        splat_rec(q.z, q.w, acc64);
    }
    if ((cnt & 1u) && tid == 0) {
        const uint2 r = recs[cnt - 1];
        splat_rec(r.x, r.y, acc64);
    }

    // fused spill application (normally zero records)
    const unsigned nsp = min(*spillcnt, (unsigned)SPILL_CAP);
    for (unsigned i = tid; i < nsp; i += 256) {
        const float4 s = spill[i];
        const unsigned meta = __float_as_uint(s.w);
        if ((int)((meta >> 1) & 3u) != myb) continue;
        if (meta & 0x80000000u) {   // restricted to one dest tile
            if ((int)((meta >> 8) & 31u) != sy || (int)((meta >> 16) & 31u) != sx)
                continue;
        }
        const int p = (int)(meta & 1u);
        const float wy = s.x, wx = s.y, nts = s.z;
        const float byf = floorf(wy), bxf = floorf(wx);
        const int iy0 = (int)byf, ix0 = (int)bxf;
        const float ay = wy - byf, ax = wx - bxf;
        const float wyv[2] = {1.0f - ay, ay};
        const float wxv[2] = {1.0f - ax, ax};
        unsigned long long* accp = acc64 + (p ? 0 : 1) * ACC_PLANE;
        #pragma unroll
        for (int dy = 0; dy < 2; ++dy) {
            const int gy = iy0 + dy;
            if ((gy >> 4) != sy) continue;       // ownership (global coords)
            #pragma unroll
            for (int dx = 0; dx < 2; ++dx) {
                const int gx = ix0 + dx;
                if ((gx >> 5) != sx) continue;
                const float w = wyv[dy] * wxv[dx];
                const unsigned qw  = __float2uint_rn(w * Q20);
                const unsigned qwt = __float2uint_rn(w * nts * Q20);
                atomicAdd(&accp[(gy & 15) * OT_W + (gx & 31)],
                          ((unsigned long long)qwt << 32) | (unsigned long long)qw);
            }
        }
    }
    __syncthreads();

    const int y0 = sy * OT_H;
    const int x0 = sx * OT_W;
    float* outb = out + (size_t)myb * 4 * IMG_H * IMG_W;
    {
        const int q = tid;                       // 0..255
        const int pl  = q / (ACC_PLANE / 4);     // 0 = pos, 1 = neg
        const int rem = q % (ACC_PLANE / 4);
        const int ry  = rem / (OT_W / 4);
        const int rx4 = rem % (OT_W / 4);
        float4 c4, t4;
        const unsigned long long* cell = acc64 + pl * ACC_PLANE + rem * 4;
        float* c = &c4.x; float* t = &t4.x;
        #pragma unroll
        for (int j = 0; j < 4; ++j) {
            const unsigned long long v = cell[j];
            c[j] = (float)(unsigned)(v & 0xFFFFFFFFull) * INV_Q20;
            t[j] = (float)(unsigned)(v >> 32) * INV_Q20;
        }
        const size_t off = (size_t)(y0 + ry) * IMG_W + x0 + rx4 * 4;
        *(float4*)(outb + (size_t)pl * IMG_H * IMG_W + off) = c4;
        *(float4*)(outb + (size_t)(pl + 2) * IMG_H * IMG_W + off) = t4;
    }
}

// ---------------------------------------------------------------------------
// Last-resort fallback: direct global atomics (needs zeroed out).
__global__ void __launch_bounds__(256)
event_splat_fallback(const float* __restrict__ flow, const float* __restrict__ ts,
                     const int* __restrict__ ev_y, const int* __restrict__ ev_x,
                     const int* __restrict__ pol, float* __restrict__ out,
                     int N, int total) {
    const int i = blockIdx.x * blockDim.x + threadIdx.x;
    if (i >= total) return;
    const int b = i / N;
    float wy, wx, nts;
    warp_from(flow, b, ev_y[i], ev_x[i], ts[i], wy, wx, nts);
    const int p = pol[i];
    const float byf = floorf(wy), bxf = floorf(wx);
    const int iy0 = (int)byf, ix0 = (int)bxf;
    const float ay = wy - byf, ax = wx - bxf;
    const float wyv[2] = {1.0f - ay, ay};
    const float wxv[2] = {1.0f - ax, ax};
    float* out_c = out + ((size_t)b * 4 + (p ? 0 : 1)) * IMG_H * IMG_W;
    float* out_t = out_c + 2 * IMG_H * IMG_W;
    #pragma unroll
    for (int dy = 0; dy < 2; ++dy) {
        const int gy = iy0 + dy;
        if (gy < 0 || gy >= IMG_H) continue;
        #pragma unroll
        for (int dx = 0; dx < 2; ++dx) {
            const int gx = ix0 + dx;
            if (gx < 0 || gx >= IMG_W) continue;
            const float w = wyv[dy] * wxv[dx];
            const int o = gy * IMG_W + gx;
            atomicAdd(out_c + o, w);
            atomicAdd(out_t + o, w * nts);
        }
    }
}

// ---------------------------------------------------------------------------
extern "C" void kernel_launch(void* const* d_in, const int* in_sizes, int n_in,
                              void* d_out, int out_size, void* d_ws, size_t ws_size,
                              hipStream_t stream) {
    const float* flow = (const float*)d_in[0];
    const float* ts   = (const float*)d_in[1];
    const int*   ev_y = (const int*)d_in[2];
    const int*   ev_x = (const int*)d_in[3];
    const int*   pol  = (const int*)d_in[4];
    float* out = (float*)d_out;

    const int total = in_sizes[2];                  // B*N
    const int B = out_size / (4 * IMG_H * IMG_W);
    const int N = total / B;
    char* ws = (char*)d_ws;

    // cap slots per dest tile: drec 8 B/slot. mean ~548, sigma ~23;
    // cap >= 704 -> overflow ~never (spill path covers it regardless).
    int cap = 0;
    if (ws_size > (size_t)WS_RECS)
        cap = (int)((ws_size - WS_RECS) / ((size_t)NT * 8));
    if (cap > 1024) cap = 1024;
    cap &= ~3;

    if (B == NB && cap >= 704) {
        unsigned* dcurs    = (unsigned*)(ws + WS_CURS);
        unsigned* spillcnt = (unsigned*)(ws + WS_SPILLCNT);
        float4*   spill    = (float4*)(ws + WS_SPILL);
        uint2*    drecs    = (uint2*)(ws + WS_RECS);

        hipMemsetAsync(ws, 0, WS_SPILL, stream);    // dcurs + spillcnt

        dim3 g1((N + K1_CHUNK - 1) / K1_CHUNK, NB);
        warp_scatter_kernel<<<g1, K1_THREADS, 0, stream>>>(
            flow, ts, ev_y, ev_x, pol, dcurs, spillcnt, spill, drecs, N, cap);
        splat_kernel<<<NT, 256, 0, stream>>>(drecs, dcurs, spill, spillcnt,
                                             out, cap);
        return;
    }

    // last resort
    hipMemsetAsync(d_out, 0, (size_t)out_size * sizeof(float), stream);
    const int blocks = (total + 255) / 256;
    event_splat_fallback<<<blocks, 256, 0, stream>>>(flow, ts, ev_y, ev_x, pol,
                                                     out, N, total);
}

// Round 12
// 128.793 us; speedup vs baseline: 1.2343x; 1.1234x over previous
//
#include <hip/hip_runtime.h>

// Event-warp + bilinear splat, v12 = v11 + XCD-affinity block swizzle.
//   K1 warp_scatter: warp events (random flow gather) + direct dest-tile
//       counting scatter (LDS hist+rank, padded cursors, 8-B records).
//       1-D grid swizzled so batch b runs on XCDs {2b,2b+1} -> per-XCD L2
//       holds ONE batch's 4.9 MB flow instead of thrashing on all four.
//   K2 splat: one block per ownership tile, same swizzle (drec L2 affinity);
//       paired uint4 loads; (w, w*nts) Q20-packed ds_add_u64; fused spill;
//       pure float4 writeout (no out-memset needed).
// Inputs (setup_inputs order):
//   d_in[0] flow  : float32 [B,2,H,W]   (ch0 = x-flow, ch1 = y-flow)
//   d_in[1] ts    : float32 [B,N,1]
//   d_in[2] ev_y  : int32   [B,N]
//   d_in[3] ev_x  : int32   [B,N]
//   d_in[4] pol   : int32   [B,N]  (1 = positive, 0 = negative)
// Output: float32 [B,4,H,W] = (iwe_pos, iwe_neg, iwe_pos_ts, iwe_neg_ts)

#define IMG_H 480
#define IMG_W 640

#define OT_H 16
#define OT_W 32
#define OTY (IMG_H / OT_H)        // 30
#define OTX (IMG_W / OT_W)        // 20
#define OT_PER_B (OTY * OTX)      // 600
#define NB 4
#define NT (NB * OT_PER_B)        // 2400

#define ACC_PLANE (OT_H * OT_W)   // 512 cells

// ws layout (byte offsets)
#define CURS_STRIDE 16                  // u32 stride -> 64 B padded lines
#define WS_CURS 0                       // NT * 64 B = 153600
#define WS_SPILLCNT 163200              // 4 B
#define WS_SPILL 163840                 // SPILL_CAP * 16 B = 512 KB
#define SPILL_CAP 32768
#define WS_RECS 688128                  // drecs: NT * cap * 8 B

#define K1_THREADS 256
#define K1_IPT 4
#define K1_CHUNK (K1_THREADS * K1_IPT)  // 1024 events per block

#define Q20 1048576.0f
#define INV_Q20 9.5367431640625e-07f

// ---------------------------------------------------------------------------
__device__ __forceinline__ void
warp_from(const float* __restrict__ flow, int b, int y, int x, float t,
          float& wy, float& wx, float& nts) {
    const float* fb = flow + (size_t)b * 2 * IMG_H * IMG_W;
    const int pix = y * IMG_W + x;
    const float fx = fb[pix];
    const float fy = fb[IMG_H * IMG_W + pix];
    const float dt = 1.0f - t;
    wy = (float)y + dt * fy;
    wx = (float)x + dt * fx;
    nts = 1.0f - fabsf(1.0f - t);
}

// ---------------------------------------------------------------------------
// K1: warp + direct dest-tile counting scatter. XCD-affinity swizzle:
// block L -> XCD L%8 (heuristic); batch = bits[2:1] of L -> XCDs {2b,2b+1}.
__global__ void __launch_bounds__(K1_THREADS)
warp_scatter_kernel(const float* __restrict__ flow, const float* __restrict__ ts,
                    const int* __restrict__ ev_y, const int* __restrict__ ev_x,
                    const int* __restrict__ pol,
                    unsigned* __restrict__ dcurs, unsigned* __restrict__ spillcnt,
                    float4* __restrict__ spill, uint2* __restrict__ drecs,
                    int N, int cap, int nchunk) {
    __shared__ unsigned lh[OT_PER_B];     // per-dest-tile block-local counts
    __shared__ unsigned lbase[OT_PER_B];  // reserved global bases
    const int tid = threadIdx.x;
    const int L = blockIdx.x;
    const int b = (L >> 1) & 3;                    // batch -> XCD pair
    const int chunk = (L >> 3) * 2 + (L & 1);
    if (chunk >= nchunk) return;
    const int base = chunk * K1_CHUNK;

    for (int j = tid; j < OT_PER_B; j += K1_THREADS) lh[j] = 0;
    __syncthreads();

    // Phase A: warp + LDS rank. dups packed as (lt << 16 | rank).
    float wyK[K1_IPT], wxK[K1_IPT];
    unsigned metaK[K1_IPT];               // qt | pol<<15 (drec.y)
    unsigned ndK[K1_IPT];
    unsigned dupK[K1_IPT][4];

    #pragma unroll
    for (int k = 0; k < K1_IPT; ++k) {
        unsigned nd = 0;
        float wy = 0.f, wx = 0.f;
        unsigned meta = 0;
        const int idx = base + k * K1_THREADS + tid;
        if (idx < N) {
            const int i = b * N + idx;
            float nts;
            warp_from(flow, b, ev_y[i], ev_x[i], ts[i], wy, wx, nts);
            const int p = pol[i] & 1;
            int qt = __float2int_rn(nts * 32767.0f);
            qt = min(max(qt, 0), 32767);
            meta = (unsigned)qt | ((unsigned)p << 15);

            const int iy0 = (int)floorf(wy);
            const int ix0 = (int)floorf(wx);
            int rys[2]; int nry = 0;
            if (iy0 >= 0 && iy0 < IMG_H) rys[nry++] = iy0 >> 4;
            if (iy0 + 1 >= 0 && iy0 + 1 < IMG_H) {
                const int r = (iy0 + 1) >> 4;
                if (nry == 0 || r != rys[0]) rys[nry++] = r;
            }
            int rxs[2]; int nrx = 0;
            if (ix0 >= 0 && ix0 < IMG_W) rxs[nrx++] = ix0 >> 5;
            if (ix0 + 1 >= 0 && ix0 + 1 < IMG_W) {
                const int r = (ix0 + 1) >> 5;
                if (nrx == 0 || r != rxs[0]) rxs[nrx++] = r;
            }
            for (int a = 0; a < nry; ++a)
                for (int c = 0; c < nrx; ++c) {
                    const unsigned lt = (unsigned)(rys[a] * OTX + rxs[c]);
                    const unsigned rk = atomicAdd(&lh[lt], 1u);
                    dupK[k][nd++] = (lt << 16) | rk;
                }
        }
        wyK[k] = wy; wxK[k] = wx; metaK[k] = meta; ndK[k] = nd;
    }
    __syncthreads();

    // Phase B: reserve per-tile global ranges (1 padded atomic per nonzero)
    for (int j = tid; j < OT_PER_B; j += K1_THREADS) {
        const unsigned n = lh[j];
        lbase[j] = n ? atomicAdd(&dcurs[(size_t)(b * OT_PER_B + j) * CURS_STRIDE], n)
                     : 0u;
    }
    __syncthreads();

    // Phase C: write dest-quantized records
    #pragma unroll
    for (int k = 0; k < K1_IPT; ++k) {
        const unsigned nd = ndK[k];
        for (unsigned d = 0; d < nd; ++d) {
            const unsigned lt = dupK[k][d] >> 16;
            const unsigned rk = dupK[k][d] & 0xFFFFu;
            const int dty = (int)(lt / OTX);
            const int dtx = (int)(lt % OTX);
            const unsigned slot = lbase[lt] + rk;
            if (slot < (unsigned)cap) {
                int qy = __float2int_rn((wyK[k] - 16.0f * dty + 1.0f) * 2048.0f);
                int qx = __float2int_rn((wxK[k] - 32.0f * dtx + 1.0f) * 1024.0f);
                qy = min(max(qy, 0), 65535);
                qx = min(max(qx, 0), 65535);
                uint2 dr;
                dr.x = (unsigned)qy | ((unsigned)qx << 16);
                dr.y = metaK[k];
                drecs[(size_t)(b * OT_PER_B + lt) * cap + slot] = dr;
            } else {
                // restricted spill: applied only by tile (dty,dtx)
                const unsigned g = atomicAdd(spillcnt, 1u);
                if (g < SPILL_CAP) {
                    float4 s;
                    s.x = wyK[k]; s.y = wxK[k];
                    s.z = (float)(metaK[k] & 0x7FFFu) * (1.0f / 32767.0f);
                    s.w = __uint_as_float(0x80000000u
                            | (unsigned)((b << 1) | (metaK[k] >> 15))
                            | ((unsigned)dty << 8) | ((unsigned)dtx << 16));
                    spill[g] = s;
                }
            }
        }
    }
}

// ---------------------------------------------------------------------------
// K2: one block per ownership tile, same XCD-affinity swizzle.
__device__ __forceinline__ void
splat_rec(unsigned rx_, unsigned ry_, unsigned long long* __restrict__ acc64) {
    const float ry  = (float)(rx_ & 0xFFFFu) * (1.0f / 2048.0f) - 1.0f;
    const float rx  = (float)(rx_ >> 16)     * (1.0f / 1024.0f) - 1.0f;
    const float nts = (float)(ry_ & 0x7FFFu) * (1.0f / 32767.0f);
    const int p = (int)((ry_ >> 15) & 1u);
    const float byf = floorf(ry), bxf = floorf(rx);
    const int iy0 = (int)byf, ix0 = (int)bxf;
    const float ay = ry - byf, ax = rx - bxf;
    const float wyv[2] = {1.0f - ay, ay};
    const float wxv[2] = {1.0f - ax, ax};
    unsigned long long* accp = acc64 + (p ? 0 : 1) * ACC_PLANE;
    #pragma unroll
    for (int dy = 0; dy < 2; ++dy) {
        const int gy = iy0 + dy;
        if ((unsigned)gy >= (unsigned)OT_H) continue;
        #pragma unroll
        for (int dx = 0; dx < 2; ++dx) {
            const int gx = ix0 + dx;
            if ((unsigned)gx >= (unsigned)OT_W) continue;
            const float w = wyv[dy] * wxv[dx];
            const unsigned qw  = __float2uint_rn(w * Q20);
            const unsigned qwt = __float2uint_rn(w * nts * Q20);
            atomicAdd(&accp[gy * OT_W + gx],
                      ((unsigned long long)qwt << 32) | (unsigned long long)qw);
        }
    }
}

__global__ void __launch_bounds__(256)
splat_kernel(const uint2* __restrict__ drecs, const unsigned* __restrict__ dcurs,
             const float4* __restrict__ spill, const unsigned* __restrict__ spillcnt,
             float* __restrict__ out, int cap) {
    __shared__ unsigned long long acc64[2 * ACC_PLANE];  // [pol(pos,neg)][cell]
    const int L = blockIdx.x;
    const int myb = (L >> 1) & 3;                  // batch -> XCD pair
    const int rb  = (L >> 3) * 2 + (L & 1);        // 0..599
    const int tile = myb * OT_PER_B + rb;
    const int tid = threadIdx.x;
    #pragma unroll
    for (int j = tid; j < 2 * ACC_PLANE; j += 256) acc64[j] = 0ull;
    __syncthreads();

    const int sy  = rb / OTX;
    const int sx  = rb % OTX;

    const unsigned cnt = min(dcurs[(size_t)tile * CURS_STRIDE], (unsigned)cap);
    const uint2* recs = drecs + (size_t)tile * cap;
    const uint4* base4 = (const uint4*)recs;
    const unsigned npair = cnt >> 1;
    for (unsigned u = tid; u < npair; u += 256) {
        const uint4 q = base4[u];          // two records
        splat_rec(q.x, q.y, acc64);
        splat_rec(q.z, q.w, acc64);
    }
    if ((cnt & 1u) && tid == 0) {
        const uint2 r = recs[cnt - 1];
        splat_rec(r.x, r.y, acc64);
    }

    // fused spill application (normally zero records)
    const unsigned nsp = min(*spillcnt, (unsigned)SPILL_CAP);
    for (unsigned i = tid; i < nsp; i += 256) {
        const float4 s = spill[i];
        const unsigned meta = __float_as_uint(s.w);
        if ((int)((meta >> 1) & 3u) != myb) continue;
        if (meta & 0x80000000u) {   // restricted to one dest tile
            if ((int)((meta >> 8) & 31u) != sy || (int)((meta >> 16) & 31u) != sx)
                continue;
        }
        const int p = (int)(meta & 1u);
        const float wy = s.x, wx = s.y, nts = s.z;
        const float byf = floorf(wy), bxf = floorf(wx);
        const int iy0 = (int)byf, ix0 = (int)bxf;
        const float ay = wy - byf, ax = wx - bxf;
        const float wyv[2] = {1.0f - ay, ay};
        const float wxv[2] = {1.0f - ax, ax};
        unsigned long long* accp = acc64 + (p ? 0 : 1) * ACC_PLANE;
        #pragma unroll
        for (int dy = 0; dy < 2; ++dy) {
            const int gy = iy0 + dy;
            if ((gy >> 4) != sy) continue;       // ownership (global coords)
            #pragma unroll
            for (int dx = 0; dx < 2; ++dx) {
                const int gx = ix0 + dx;
                if ((gx >> 5) != sx) continue;
                const float w = wyv[dy] * wxv[dx];
                const unsigned qw  = __float2uint_rn(w * Q20);
                const unsigned qwt = __float2uint_rn(w * nts * Q20);
                atomicAdd(&accp[(gy & 15) * OT_W + (gx & 31)],
                          ((unsigned long long)qwt << 32) | (unsigned long long)qw);
            }
        }
    }
    __syncthreads();

    const int y0 = sy * OT_H;
    const int x0 = sx * OT_W;
    float* outb = out + (size_t)myb * 4 * IMG_H * IMG_W;
    {
        const int q = tid;                       // 0..255
        const int pl  = q / (ACC_PLANE / 4);     // 0 = pos, 1 = neg
        const int rem = q % (ACC_PLANE / 4);
        const int ry  = rem / (OT_W / 4);
        const int rx4 = rem % (OT_W / 4);
        float4 c4, t4;
        const unsigned long long* cell = acc64 + pl * ACC_PLANE + rem * 4;
        float* c = &c4.x; float* t = &t4.x;
        #pragma unroll
        for (int j = 0; j < 4; ++j) {
            const unsigned long long v = cell[j];
            c[j] = (float)(unsigned)(v & 0xFFFFFFFFull) * INV_Q20;
            t[j] = (float)(unsigned)(v >> 32) * INV_Q20;
        }
        const size_t off = (size_t)(y0 + ry) * IMG_W + x0 + rx4 * 4;
        *(float4*)(outb + (size_t)pl * IMG_H * IMG_W + off) = c4;
        *(float4*)(outb + (size_t)(pl + 2) * IMG_H * IMG_W + off) = t4;
    }
}

// ---------------------------------------------------------------------------
// Last-resort fallback: direct global atomics (needs zeroed out).
__global__ void __launch_bounds__(256)
event_splat_fallback(const float* __restrict__ flow, const float* __restrict__ ts,
                     const int* __restrict__ ev_y, const int* __restrict__ ev_x,
                     const int* __restrict__ pol, float* __restrict__ out,
                     int N, int total) {
    const int i = blockIdx.x * blockDim.x + threadIdx.x;
    if (i >= total) return;
    const int b = i / N;
    float wy, wx, nts;
    warp_from(flow, b, ev_y[i], ev_x[i], ts[i], wy, wx, nts);
    const int p = pol[i];
    const float byf = floorf(wy), bxf = floorf(wx);
    const int iy0 = (int)byf, ix0 = (int)bxf;
    const float ay = wy - byf, ax = wx - bxf;
    const float wyv[2] = {1.0f - ay, ay};
    const float wxv[2] = {1.0f - ax, ax};
    float* out_c = out + ((size_t)b * 4 + (p ? 0 : 1)) * IMG_H * IMG_W;
    float* out_t = out_c + 2 * IMG_H * IMG_W;
    #pragma unroll
    for (int dy = 0; dy < 2; ++dy) {
        const int gy = iy0 + dy;
        if (gy < 0 || gy >= IMG_H) continue;
        #pragma unroll
        for (int dx = 0; dx < 2; ++dx) {
            const int gx = ix0 + dx;
            if (gx < 0 || gx >= IMG_W) continue;
            const float w = wyv[dy] * wxv[dx];
            const int o = gy * IMG_W + gx;
            atomicAdd(out_c + o, w);
            atomicAdd(out_t + o, w * nts);
        }
    }
}

// ---------------------------------------------------------------------------
extern "C" void kernel_launch(void* const* d_in, const int* in_sizes, int n_in,
                              void* d_out, int out_size, void* d_ws, size_t ws_size,
                              hipStream_t stream) {
    const float* flow = (const float*)d_in[0];
    const float* ts   = (const float*)d_in[1];
    const int*   ev_y = (const int*)d_in[2];
    const int*   ev_x = (const int*)d_in[3];
    const int*   pol  = (const int*)d_in[4];
    float* out = (float*)d_out;

    const int total = in_sizes[2];                  // B*N
    const int B = out_size / (4 * IMG_H * IMG_W);
    const int N = total / B;
    char* ws = (char*)d_ws;

    // cap slots per dest tile: drec 8 B/slot.
    int cap = 0;
    if (ws_size > (size_t)WS_RECS)
        cap = (int)((ws_size - WS_RECS) / ((size_t)NT * 8));
    if (cap > 1024) cap = 1024;
    cap &= ~3;

    if (B == NB && cap >= 704) {
        unsigned* dcurs    = (unsigned*)(ws + WS_CURS);
        unsigned* spillcnt = (unsigned*)(ws + WS_SPILLCNT);
        float4*   spill    = (float4*)(ws + WS_SPILL);
        uint2*    drecs    = (uint2*)(ws + WS_RECS);

        hipMemsetAsync(ws, 0, WS_SPILL, stream);    // dcurs + spillcnt

        const int nchunk = (N + K1_CHUNK - 1) / K1_CHUNK;            // 293
        const int g1 = 8 * ((nchunk + 1) / 2);                       // 1176
        warp_scatter_kernel<<<g1, K1_THREADS, 0, stream>>>(
            flow, ts, ev_y, ev_x, pol, dcurs, spillcnt, spill, drecs,
            N, cap, nchunk);
        splat_kernel<<<NT, 256, 0, stream>>>(drecs, dcurs, spill, spillcnt,
                                             out, cap);
        return;
    }

    // last resort
    hipMemsetAsync(d_out, 0, (size_t)out_size * sizeof(float), stream);
    const int blocks = (total + 255) / 256;
    event_splat_fallback<<<blocks, 256, 0, stream>>>(flow, ts, ev_y, ev_x, pol,
                                                     out, N, total);
}